// Round 17
// baseline (779.791 us; speedup 1.0000x reference)
//
#include <hip/hip_runtime.h>
#include <hip/hip_bf16.h>

typedef __attribute__((ext_vector_type(8))) short short8;
typedef __attribute__((ext_vector_type(4))) float f32x4;
typedef unsigned short u16;
typedef unsigned int u32;

#define NTOK   8192
#define DMODEL 1024
#define DFF    4096
#define NEXP   8
#define NPAIR  (NTOK * 2)
#define PADM   128            // per-expert padding = M-tile granularity
#define PPAD   (136 * 128)    // 17408 = worst case sum of per-expert ceils

// ---- workspace layout (bytes) ----
#define OFF_XB   0ull
#define OFF_W1T  (OFF_XB  + (size_t)NTOK * DMODEL * 2)
#define OFF_W2T  (OFF_W1T + (size_t)NEXP * DFF * DMODEL * 2)
#define OFF_W3T  (OFF_W2T + (size_t)NEXP * DFF * DMODEL * 2)
#define OFF_H    (OFF_W3T + (size_t)NEXP * DMODEL * DFF * 2)
#define OFF_TOK  (OFF_H   + (size_t)PPAD * DFF * 2)
#define OFF_WGT  (OFF_TOK + (size_t)PPAD * 4)
#define OFF_OFFP (OFF_WGT + (size_t)PPAD * 4)
#define OFF_INV  (OFF_OFFP + 64)
#define WS_END   (OFF_INV + (size_t)NPAIR * 4)
// ph (stage2 partials, PPAD x 1024 f32 = 71.3 MB) aliases w1t/w2t (134 MB),
// which are dead after stage1_k. Rewritten by wcvt_k on every replay.
#define OFF_PH   OFF_W1T

#define GLOAD16(gp, lp)                                                        \
  __builtin_amdgcn_global_load_lds(                                            \
      (const __attribute__((address_space(1))) u32*)(gp),                      \
      (__attribute__((address_space(3))) u32*)(lp), 16, 0, 0)

__device__ __forceinline__ u16 f2bu(float f) {
  __hip_bfloat16 b = __float2bfloat16(f);
  return __builtin_bit_cast(u16, b);
}

// ---------------- conversion kernels ----------------

__global__ __launch_bounds__(256) void cvt_x_k(const float* __restrict__ x,
                                               u16* __restrict__ xb) {
  int i = blockIdx.x * 256 + threadIdx.x;
  float4 v = ((const float4*)x)[i];
  unsigned long long pk = (unsigned long long)f2bu(v.x) |
                          ((unsigned long long)f2bu(v.y) << 16) |
                          ((unsigned long long)f2bu(v.z) << 32) |
                          ((unsigned long long)f2bu(v.w) << 48);
  ((unsigned long long*)xb)[i] = pk;
}

// Fused weight transpose+convert: [R][C] fp32 -> [C][R] bf16 for w1,w2,w3.
__global__ __launch_bounds__(256) void wcvt_k(const float* __restrict__ w1,
                                              const float* __restrict__ w2,
                                              const float* __restrict__ w3,
                                              u16* __restrict__ w1t,
                                              u16* __restrict__ w2t,
                                              u16* __restrict__ w3t) {
  const int z = blockIdx.y;
  const float* src; u16* dst; int R, C, tx, ty;
  if (z < 16) {
    R = DMODEL; C = DFF;
    int e = z & 7;
    src = ((z < 8) ? w1 : w2) + (size_t)e * R * C;
    dst = ((z < 8) ? w1t : w2t) + (size_t)e * R * C;
    tx = blockIdx.x & 63; ty = blockIdx.x >> 6;     // 64 x 4
  } else {
    R = DFF; C = DMODEL;
    int e = z - 16;
    src = w3 + (size_t)e * R * C;
    dst = w3t + (size_t)e * R * C;
    tx = blockIdx.x & 15; ty = blockIdx.x >> 4;     // 16 x 16
  }
  const int c0 = tx * 64, r0 = ty * 256;
  __shared__ u16 t[256][68];
  const int tid = threadIdx.x;
  const int cl = (tid & 15) * 4, rl = tid >> 4;
#pragma unroll
  for (int p = 0; p < 16; ++p) {
    int r = rl + p * 16;
    float4 v = *(const float4*)(src + (size_t)(r0 + r) * C + c0 + cl);
    unsigned long long pk = (unsigned long long)f2bu(v.x) |
                            ((unsigned long long)f2bu(v.y) << 16) |
                            ((unsigned long long)f2bu(v.z) << 32) |
                            ((unsigned long long)f2bu(v.w) << 48);
    *(unsigned long long*)&t[r][cl] = pk;
  }
  __syncthreads();
  const int c = tid >> 2, seg = tid & 3;
#pragma unroll
  for (int u = 0; u < 8; ++u) {
    int rbase = seg * 8 + u * 32;
    short8 o;
#pragma unroll
    for (int j = 0; j < 8; ++j) o[j] = (short)t[rbase + j][c];
    *(short8*)(dst + (size_t)(c0 + c) * R + r0 + rbase) = o;
  }
}

// ---------------- routing: init + count + scan + scatter, one block -------

__global__ __launch_bounds__(1024) void route_k(const int* __restrict__ ei,
                                                const float* __restrict__ ew,
                                                int* __restrict__ tok,
                                                float* __restrict__ wg,
                                                int* __restrict__ offp_g,
                                                int* __restrict__ inv) {
  __shared__ int cnt[NEXP], offp[NEXP + 1], cur[NEXP];
  const int tid = threadIdx.x;
  if (tid < NEXP) { cnt[tid] = 0; cur[tid] = 0; }
  __syncthreads();
  for (int i = tid; i < PPAD; i += 1024) { tok[i] = 0; wg[i] = 0.f; }
  for (int i = tid; i < NPAIR; i += 1024) {
    int e = ei[i];
#pragma unroll
    for (int x = 0; x < NEXP; ++x) {
      unsigned long long m = __ballot(e == x);
      if ((tid & 63) == 0 && m) atomicAdd(&cnt[x], (int)__popcll(m));
    }
  }
  __syncthreads();
  if (tid == 0) {
    int a = 0;
#pragma unroll
    for (int e = 0; e < NEXP; ++e) { offp[e] = a; a += (cnt[e] + PADM - 1) & ~(PADM - 1); }
    offp[NEXP] = a;
  }
  __syncthreads();
  for (int i = tid; i < NPAIR; i += 1024) {
    int e = ei[i];
    int p = offp[e] + atomicAdd(&cur[e], 1);
    tok[p] = i >> 1;
    wg[p] = ew[i];
    inv[i] = p;                 // token (i>>1), slot (i&1) -> padded position
  }
  if (tid <= NEXP) offp_g[tid] = offp[tid];
}

// ---------------- stage 1: h = silu(x@W1) * (x@W2), grouped ----------------
// r13/r16 best-known-good, NO swizzle (natural dispatch keeps each expert's
// weight panel hot in L2/L3 across its M-strip sequence). Tile 128x128,
// BK=32, 3-buffer counted vmcnt(3), 1 barrier/step, 2 blocks/CU (72 KB LDS).

#define S1_BUF 12288   // u16 per buffer: A 4096 | B1 4096 | B2 4096
#define S1_NK  32      // 1024 / 32

__global__ __launch_bounds__(512, 4) void stage1_k(const u16* __restrict__ xb,
                                                   const u16* __restrict__ w1t,
                                                   const u16* __restrict__ w2t,
                                                   u16* __restrict__ h,
                                                   const int* __restrict__ tok,
                                                   const int* __restrict__ offp) {
  extern __shared__ __align__(16) u16 lds[];   // 3 * 24576 B = 73728 B
  const int r0 = blockIdx.y * 128;
  if (r0 >= offp[NEXP]) return;
  int e = 0;
#pragma unroll
  for (int q = 0; q < 7; ++q) e += (offp[e + 1] <= r0) ? 1 : 0;
  const int n0 = blockIdx.x * 128;
  const int tid = threadIdx.x;
  const int lane = tid & 63, w = tid >> 6;
  const int wm = w >> 2, wn = w & 3;

  const int sl = lane & 3, rl = lane >> 2;
  const u16* aga;
  int adb;
  {
    int row = w * 16 + rl;
    int t = tok[r0 + row];
    aga = xb + (size_t)t * DMODEL + ((sl ^ ((row >> 1) & 3)) << 3);
    adb = (w * 16) * 32;
  }
  const u16* w1e = w1t + (size_t)e * DFF * DMODEL;
  const u16* w2e = w2t + (size_t)e * DFF * DMODEL;
  const u16* bg1; const u16* bg2;
  int bdb;
  {
    int row = w * 16 + rl;
    size_t ro = (size_t)(n0 + row) * DMODEL + ((sl ^ ((row >> 1) & 3)) << 3);
    bg1 = w1e + ro; bg2 = w2e + ro;
    bdb = (w * 16) * 32;
  }

  int aoff[4], boff[2];
  {
    int ks = lane >> 4;
#pragma unroll
    for (int mi = 0; mi < 4; ++mi) {
      int row = wm * 64 + mi * 16 + (lane & 15);
      aoff[mi] = row * 32 + ((ks ^ ((row >> 1) & 3)) << 3);
    }
#pragma unroll
    for (int ni = 0; ni < 2; ++ni) {
      int col = wn * 32 + ni * 16 + (lane & 15);
      boff[ni] = col * 32 + ((ks ^ ((col >> 1) & 3)) << 3);
    }
  }

  f32x4 accg[4][2], accv[4][2];
  const f32x4 zero = {0.f, 0.f, 0.f, 0.f};
#pragma unroll
  for (int mi = 0; mi < 4; ++mi)
#pragma unroll
    for (int ni = 0; ni < 2; ++ni) { accg[mi][ni] = zero; accv[mi][ni] = zero; }

#define S1_ISSUE(Q, KO)                                                        \
  do {                                                                         \
    GLOAD16(aga + (KO), (Q) + adb);                                            \
    GLOAD16(bg1 + (KO), (Q) + 4096 + bdb);                                     \
    GLOAD16(bg2 + (KO), (Q) + 8192 + bdb);                                     \
  } while (0)

  S1_ISSUE(lds, 0);
  S1_ISSUE(lds + S1_BUF, 32);
  asm volatile("s_waitcnt vmcnt(3)" ::: "memory");
  __builtin_amdgcn_s_barrier();
  __builtin_amdgcn_sched_barrier(0);

#define S1_STEP(P, KC, ISSUE)                                                  \
  {                                                                            \
    const u16* Ab  = lds + (P) * S1_BUF;                                       \
    const u16* B1b = Ab + 4096;                                                \
    const u16* B2b = Ab + 8192;                                                \
    short8 af[4], b1f[2], b2f[2];                                              \
    _Pragma("unroll") for (int mi = 0; mi < 4; ++mi)                           \
      af[mi] = *(const short8*)(Ab + aoff[mi]);                                \
    _Pragma("unroll") for (int ni = 0; ni < 2; ++ni) {                         \
      b1f[ni] = *(const short8*)(B1b + boff[ni]);                              \
      b2f[ni] = *(const short8*)(B2b + boff[ni]);                              \
    }                                                                          \
    if (ISSUE) S1_ISSUE(lds + (((P) + 2) % 3) * S1_BUF, ((KC) + 2) * 32);      \
    __builtin_amdgcn_s_setprio(1);                                             \
    _Pragma("unroll") for (int mi = 0; mi < 4; ++mi)                           \
      _Pragma("unroll") for (int ni = 0; ni < 2; ++ni) {                       \
        accg[mi][ni] = __builtin_amdgcn_mfma_f32_16x16x32_bf16(                \
            af[mi], b1f[ni], accg[mi][ni], 0, 0, 0);                           \
        accv[mi][ni] = __builtin_amdgcn_mfma_f32_16x16x32_bf16(                \
            af[mi], b2f[ni], accv[mi][ni], 0, 0, 0);                           \
      }                                                                        \
    __builtin_amdgcn_s_setprio(0);                                             \
    if (ISSUE) asm volatile("s_waitcnt vmcnt(3)" ::: "memory");                \
    else       asm volatile("s_waitcnt vmcnt(0)" ::: "memory");                \
    __builtin_amdgcn_s_barrier();                                              \
    __builtin_amdgcn_sched_barrier(0);                                         \
  }

  for (int kc = 0; kc < S1_NK - 2; kc += 3) {
    S1_STEP(0, kc, 1)
    S1_STEP(1, kc + 1, 1)
    S1_STEP(2, kc + 2, 1)
  }
  S1_STEP(0, S1_NK - 2, 0)
  S1_STEP(1, S1_NK - 1, 0)
#undef S1_STEP
#undef S1_ISSUE

  const int prow = r0 + wm * 64 + ((lane >> 4) << 2);
  const int pcol = n0 + wn * 32 + (lane & 15);
#pragma unroll
  for (int mi = 0; mi < 4; ++mi)
#pragma unroll
    for (int ni = 0; ni < 2; ++ni)
#pragma unroll
      for (int j = 0; j < 4; ++j) {
        float g = accg[mi][ni][j];
        float v = accv[mi][ni][j];
        float s = g / (1.f + __expf(-g));
        h[(size_t)(prow + mi * 16 + j) * DFF + (pcol + ni * 16)] = f2bu(s * v);
      }
}

// ---------------- stage 2: ph[pos] = wg[pos] * (h[pos] @ W3), grouped -----
// r13 structure; epilogue now writes weighted partials NON-atomically to the
// slot-indexed ph buffer (aliases dead w1t/w2t). reduce_k sums the 2 slots
// per token. Removes 17.8M fp32 global atomics.

#define S2_BUF 12288   // u16 per buffer: A 4096 (128x32) | B 8192 (256x32)
#define S2_NK  128     // 4096 / 32

__global__ __launch_bounds__(512, 4) void stage2_k(const u16* __restrict__ h,
                                                   const u16* __restrict__ w3t,
                                                   float* __restrict__ ph,
                                                   const float* __restrict__ wg,
                                                   const int* __restrict__ offp) {
  extern __shared__ __align__(16) u16 lds[];   // 3 * 24576 B = 73728 B
  const int orig = blockIdx.y * 4 + blockIdx.x;     // gridDim = (4, 136)
  const int wgid = (orig & 7) * 68 + (orig >> 3);
  const int bx = wgid & 3, by = wgid >> 2;
  const int r0 = by * 128;
  if (r0 >= offp[NEXP]) return;
  int e = 0;
#pragma unroll
  for (int q = 0; q < 7; ++q) e += (offp[e + 1] <= r0) ? 1 : 0;
  const int n0 = bx * 256;
  const int tid = threadIdx.x;
  const int lane = tid & 63, w = tid >> 6;
  const int wm = w >> 2, wn = w & 3;

  const int sl = lane & 3, rl = lane >> 2;
  const u16* aga;
  int adb;
  {
    int row = w * 16 + rl;
    aga = h + (size_t)(r0 + row) * DFF + ((sl ^ ((row >> 1) & 3)) << 3);
    adb = (w * 16) * 32;
  }
  const u16* w3e = w3t + (size_t)e * DMODEL * DFF;
  const u16* bga[2];
  int bdb[2];
#pragma unroll
  for (int j = 0; j < 2; ++j) {
    int row = w * 32 + j * 16 + rl;
    bga[j] = w3e + (size_t)(n0 + row) * DFF + ((sl ^ ((row >> 1) & 3)) << 3);
    bdb[j] = 4096 + (w * 32 + j * 16) * 32;
  }

  int aoff[4], boff[4];
  {
    int ks = lane >> 4;
#pragma unroll
    for (int mi = 0; mi < 4; ++mi) {
      int row = wm * 64 + mi * 16 + (lane & 15);
      aoff[mi] = row * 32 + ((ks ^ ((row >> 1) & 3)) << 3);
    }
#pragma unroll
    for (int ni = 0; ni < 4; ++ni) {
      int col = wn * 64 + ni * 16 + (lane & 15);
      boff[ni] = 4096 + col * 32 + ((ks ^ ((col >> 1) & 3)) << 3);
    }
  }

  f32x4 acc[4][4];
  const f32x4 zero = {0.f, 0.f, 0.f, 0.f};
#pragma unroll
  for (int mi = 0; mi < 4; ++mi)
#pragma unroll
    for (int ni = 0; ni < 4; ++ni) acc[mi][ni] = zero;

#define S2_ISSUE(Q, KO)                                                        \
  do {                                                                         \
    GLOAD16(aga + (KO), (Q) + adb);                                            \
    GLOAD16(bga[0] + (KO), (Q) + bdb[0]);                                      \
    GLOAD16(bga[1] + (KO), (Q) + bdb[1]);                                      \
  } while (0)

  S2_ISSUE(lds, 0);
  S2_ISSUE(lds + S2_BUF, 32);
  asm volatile("s_waitcnt vmcnt(3)" ::: "memory");
  __builtin_amdgcn_s_barrier();
  __builtin_amdgcn_sched_barrier(0);

#define S2_STEP(P, KC, ISSUE)                                                  \
  {                                                                            \
    const u16* Qb = lds + (P) * S2_BUF;                                        \
    short8 af[4], bf[4];                                                       \
    _Pragma("unroll") for (int mi = 0; mi < 4; ++mi)                           \
      af[mi] = *(const short8*)(Qb + aoff[mi]);                                \
    _Pragma("unroll") for (int ni = 0; ni < 4; ++ni)                           \
      bf[ni] = *(const short8*)(Qb + boff[ni]);                                \
    if (ISSUE) S2_ISSUE(lds + (((P) + 2) % 3) * S2_BUF, ((KC) + 2) * 32);      \
    __builtin_amdgcn_s_setprio(1);                                             \
    _Pragma("unroll") for (int mi = 0; mi < 4; ++mi)                           \
      _Pragma("unroll") for (int ni = 0; ni < 4; ++ni)                         \
        acc[mi][ni] = __builtin_amdgcn_mfma_f32_16x16x32_bf16(                 \
            af[mi], bf[ni], acc[mi][ni], 0, 0, 0);                             \
    __builtin_amdgcn_s_setprio(0);                                             \
    if (ISSUE) asm volatile("s_waitcnt vmcnt(3)" ::: "memory");                \
    else       asm volatile("s_waitcnt vmcnt(0)" ::: "memory");                \
    __builtin_amdgcn_s_barrier();                                              \
    __builtin_amdgcn_sched_barrier(0);                                         \
  }

  for (int kc = 0; kc < S2_NK - 2; kc += 3) {
    S2_STEP(0, kc, 1)
    S2_STEP(1, kc + 1, 1)
    S2_STEP(2, kc + 2, 1)
  }
  S2_STEP(0, S2_NK - 2, 0)
  S2_STEP(1, S2_NK - 1, 0)
#undef S2_STEP
#undef S2_ISSUE

  const int prow = r0 + wm * 64 + ((lane >> 4) << 2);
  const int pcolb = n0 + wn * 64 + (lane & 15);
#pragma unroll
  for (int mi = 0; mi < 4; ++mi)
#pragma unroll
    for (int j = 0; j < 4; ++j) {
      int pos = prow + mi * 16 + j;
      float p = wg[pos];
#pragma unroll
      for (int ni = 0; ni < 4; ++ni)
        ph[(size_t)pos * DMODEL + pcolb + ni * 16] = p * acc[mi][ni][j];
    }
}

// ---------------- reduce: out[t] = ph[inv[t][0]] + ph[inv[t][1]] ----------

__global__ __launch_bounds__(256) void reduce_k(const float* __restrict__ ph,
                                                const int* __restrict__ inv,
                                                float* __restrict__ out) {
  const int t = blockIdx.x;
  const int s0 = inv[t * 2], s1 = inv[t * 2 + 1];
  const float4* p0 = (const float4*)(ph + (size_t)s0 * DMODEL);
  const float4* p1 = (const float4*)(ph + (size_t)s1 * DMODEL);
  float4 a = p0[threadIdx.x], b = p1[threadIdx.x];
  float4 r; r.x = a.x + b.x; r.y = a.y + b.y; r.z = a.z + b.z; r.w = a.w + b.w;
  ((float4*)(out + (size_t)t * DMODEL))[threadIdx.x] = r;
}

// ---------------- launch ----------------

extern "C" void kernel_launch(void* const* d_in, const int* in_sizes, int n_in,
                              void* d_out, int out_size, void* d_ws, size_t ws_size,
                              hipStream_t stream) {
  (void)in_sizes; (void)n_in;
  const float* x  = (const float*)d_in[0];
  const int*   ei = (const int*)d_in[1];
  const float* ew = (const float*)d_in[2];
  const float* w1 = (const float*)d_in[3];
  const float* w2 = (const float*)d_in[4];
  const float* w3 = (const float*)d_in[5];
  float* out = (float*)d_out;
  char* ws = (char*)d_ws;

  hipMemsetAsync(out, 0, (size_t)out_size * sizeof(float), stream);
  if (ws_size < WS_END) return;   // ws too small: leave zeros (diagnosable absmax)

  u16* xb   = (u16*)(ws + OFF_XB);
  u16* w1t  = (u16*)(ws + OFF_W1T);
  u16* w2t  = (u16*)(ws + OFF_W2T);
  u16* w3t  = (u16*)(ws + OFF_W3T);
  u16* hb   = (u16*)(ws + OFF_H);
  int* tok  = (int*)(ws + OFF_TOK);
  float* wg = (float*)(ws + OFF_WGT);
  int* offp = (int*)(ws + OFF_OFFP);
  int* inv  = (int*)(ws + OFF_INV);
  float* ph = (float*)(ws + OFF_PH);   // aliases w1t/w2t (dead after stage1)

  hipFuncSetAttribute(reinterpret_cast<const void*>(stage1_k),
                      hipFuncAttributeMaxDynamicSharedMemorySize, 73728);
  hipFuncSetAttribute(reinterpret_cast<const void*>(stage2_k),
                      hipFuncAttributeMaxDynamicSharedMemorySize, 73728);

  cvt_x_k<<<dim3(NTOK * DMODEL / 4 / 256), 256, 0, stream>>>(x, xb);
  wcvt_k<<<dim3(256, 24), 256, 0, stream>>>(w1, w2, w3, w1t, w2t, w3t);
  route_k<<<dim3(1), 1024, 0, stream>>>(ei, ew, tok, wg, offp, inv);
  stage1_k<<<dim3(DFF / 128, PPAD / 128), 512, 73728, stream>>>(xb, w1t, w2t, hb, tok, offp);
  stage2_k<<<dim3(DMODEL / 256, PPAD / 128), 512, 73728, stream>>>(hb, w3t, ph, wg, offp);
  reduce_k<<<dim3(NTOK), 256, 0, stream>>>(ph, inv, out);
}

// Round 18
// 691.649 us; speedup vs baseline: 1.1274x; 1.1274x over previous
//
#include <hip/hip_runtime.h>
#include <hip/hip_bf16.h>

typedef __attribute__((ext_vector_type(8))) short short8;
typedef __attribute__((ext_vector_type(4))) float f32x4;
typedef unsigned short u16;
typedef unsigned int u32;

#define NTOK   8192
#define DMODEL 1024
#define DFF    4096
#define NEXP   8
#define NPAIR  (NTOK * 2)
#define PADM   128            // per-expert padding = M-tile granularity
#define PPAD   (136 * 128)    // 17408 = worst case sum of per-expert ceils

// ---- workspace layout (bytes) ----
#define OFF_XB   0ull
#define OFF_W1T  (OFF_XB  + (size_t)NTOK * DMODEL * 2)
#define OFF_W2T  (OFF_W1T + (size_t)NEXP * DFF * DMODEL * 2)
#define OFF_W3T  (OFF_W2T + (size_t)NEXP * DFF * DMODEL * 2)
#define OFF_H    (OFF_W3T + (size_t)NEXP * DMODEL * DFF * 2)
#define OFF_TOK  (OFF_H   + (size_t)PPAD * DFF * 2)
#define OFF_WGT  (OFF_TOK + (size_t)PPAD * 4)
#define OFF_OFFP (OFF_WGT + (size_t)PPAD * 4)
#define WS_END   (OFF_OFFP + 64)

#define GLOAD16(gp, lp)                                                        \
  __builtin_amdgcn_global_load_lds(                                            \
      (const __attribute__((address_space(1))) u32*)(gp),                      \
      (__attribute__((address_space(3))) u32*)(lp), 16, 0, 0)

__device__ __forceinline__ u16 f2bu(float f) {
  __hip_bfloat16 b = __float2bfloat16(f);
  return __builtin_bit_cast(u16, b);
}

// ---------------- conversion kernels ----------------

__global__ __launch_bounds__(256) void cvt_x_k(const float* __restrict__ x,
                                               u16* __restrict__ xb) {
  int i = blockIdx.x * 256 + threadIdx.x;
  float4 v = ((const float4*)x)[i];
  unsigned long long pk = (unsigned long long)f2bu(v.x) |
                          ((unsigned long long)f2bu(v.y) << 16) |
                          ((unsigned long long)f2bu(v.z) << 32) |
                          ((unsigned long long)f2bu(v.w) << 48);
  ((unsigned long long*)xb)[i] = pk;
}

// Fused weight transpose+convert: [R][C] fp32 -> [C][R] bf16 for w1,w2,w3.
__global__ __launch_bounds__(256) void wcvt_k(const float* __restrict__ w1,
                                              const float* __restrict__ w2,
                                              const float* __restrict__ w3,
                                              u16* __restrict__ w1t,
                                              u16* __restrict__ w2t,
                                              u16* __restrict__ w3t) {
  const int z = blockIdx.y;
  const float* src; u16* dst; int R, C, tx, ty;
  if (z < 16) {
    R = DMODEL; C = DFF;
    int e = z & 7;
    src = ((z < 8) ? w1 : w2) + (size_t)e * R * C;
    dst = ((z < 8) ? w1t : w2t) + (size_t)e * R * C;
    tx = blockIdx.x & 63; ty = blockIdx.x >> 6;     // 64 x 4
  } else {
    R = DFF; C = DMODEL;
    int e = z - 16;
    src = w3 + (size_t)e * R * C;
    dst = w3t + (size_t)e * R * C;
    tx = blockIdx.x & 15; ty = blockIdx.x >> 4;     // 16 x 16
  }
  const int c0 = tx * 64, r0 = ty * 256;
  __shared__ u16 t[256][68];
  const int tid = threadIdx.x;
  const int cl = (tid & 15) * 4, rl = tid >> 4;
#pragma unroll
  for (int p = 0; p < 16; ++p) {
    int r = rl + p * 16;
    float4 v = *(const float4*)(src + (size_t)(r0 + r) * C + c0 + cl);
    unsigned long long pk = (unsigned long long)f2bu(v.x) |
                            ((unsigned long long)f2bu(v.y) << 16) |
                            ((unsigned long long)f2bu(v.z) << 32) |
                            ((unsigned long long)f2bu(v.w) << 48);
    *(unsigned long long*)&t[r][cl] = pk;
  }
  __syncthreads();
  const int c = tid >> 2, seg = tid & 3;
#pragma unroll
  for (int u = 0; u < 8; ++u) {
    int rbase = seg * 8 + u * 32;
    short8 o;
#pragma unroll
    for (int j = 0; j < 8; ++j) o[j] = (short)t[rbase + j][c];
    *(short8*)(dst + (size_t)(c0 + c) * R + r0 + rbase) = o;
  }
}

// ---------------- routing: init + count + scan + scatter, one block -------

__global__ __launch_bounds__(1024) void route_k(const int* __restrict__ ei,
                                                const float* __restrict__ ew,
                                                int* __restrict__ tok,
                                                float* __restrict__ wg,
                                                int* __restrict__ offp_g) {
  __shared__ int cnt[NEXP], offp[NEXP + 1], cur[NEXP];
  const int tid = threadIdx.x;
  if (tid < NEXP) { cnt[tid] = 0; cur[tid] = 0; }
  __syncthreads();
  for (int i = tid; i < PPAD; i += 1024) { tok[i] = 0; wg[i] = 0.f; }
  for (int i = tid; i < NPAIR; i += 1024) {
    int e = ei[i];
#pragma unroll
    for (int x = 0; x < NEXP; ++x) {
      unsigned long long m = __ballot(e == x);
      if ((tid & 63) == 0 && m) atomicAdd(&cnt[x], (int)__popcll(m));
    }
  }
  __syncthreads();
  if (tid == 0) {
    int a = 0;
#pragma unroll
    for (int e = 0; e < NEXP; ++e) { offp[e] = a; a += (cnt[e] + PADM - 1) & ~(PADM - 1); }
    offp[NEXP] = a;
  }
  __syncthreads();
  for (int i = tid; i < NPAIR; i += 1024) {
    int e = ei[i];
    int p = offp[e] + atomicAdd(&cur[e], 1);
    tok[p] = i >> 1;
    wg[p] = ew[i];
  }
  if (tid <= NEXP) offp_g[tid] = offp[tid];
}

// ---------------- stage 1: h = silu(x@W1) * (x@W2), grouped ----------------
// r13/r16 best-known-good, NO swizzle (natural dispatch keeps each expert's
// weight panel hot in L2/L3 across its M-strip sequence; r15's XCD-chunked
// swizzle broke that: FETCH 240MB -> 1.1GB, +38us). Tile 128x128, BK=32,
// 3-buffer counted vmcnt(3), 1 barrier/step, 2 blocks/CU (72 KB LDS).

#define S1_BUF 12288   // u16 per buffer: A 4096 | B1 4096 | B2 4096
#define S1_NK  32      // 1024 / 32

__global__ __launch_bounds__(512, 4) void stage1_k(const u16* __restrict__ xb,
                                                   const u16* __restrict__ w1t,
                                                   const u16* __restrict__ w2t,
                                                   u16* __restrict__ h,
                                                   const int* __restrict__ tok,
                                                   const int* __restrict__ offp) {
  extern __shared__ __align__(16) u16 lds[];   // 3 * 24576 B = 73728 B
  const int r0 = blockIdx.y * 128;
  if (r0 >= offp[NEXP]) return;
  int e = 0;
#pragma unroll
  for (int q = 0; q < 7; ++q) e += (offp[e + 1] <= r0) ? 1 : 0;
  const int n0 = blockIdx.x * 128;
  const int tid = threadIdx.x;
  const int lane = tid & 63, w = tid >> 6;
  const int wm = w >> 2, wn = w & 3;

  const int sl = lane & 3, rl = lane >> 2;
  // A staging: 128 token-rows, 1 issue/thread (wave w: rows w*16..w*16+15)
  const u16* aga;
  int adb;
  {
    int row = w * 16 + rl;
    int t = tok[r0 + row];
    aga = xb + (size_t)t * DMODEL + ((sl ^ ((row >> 1) & 3)) << 3);
    adb = (w * 16) * 32;
  }
  // B staging: 128 ff-cols each for w1,w2; 1 issue/thread each
  const u16* w1e = w1t + (size_t)e * DFF * DMODEL;
  const u16* w2e = w2t + (size_t)e * DFF * DMODEL;
  const u16* bg1; const u16* bg2;
  int bdb;
  {
    int row = w * 16 + rl;
    size_t ro = (size_t)(n0 + row) * DMODEL + ((sl ^ ((row >> 1) & 3)) << 3);
    bg1 = w1e + ro; bg2 = w2e + ro;
    bdb = (w * 16) * 32;
  }

  int aoff[4], boff[2];
  {
    int ks = lane >> 4;
#pragma unroll
    for (int mi = 0; mi < 4; ++mi) {
      int row = wm * 64 + mi * 16 + (lane & 15);
      aoff[mi] = row * 32 + ((ks ^ ((row >> 1) & 3)) << 3);
    }
#pragma unroll
    for (int ni = 0; ni < 2; ++ni) {
      int col = wn * 32 + ni * 16 + (lane & 15);
      boff[ni] = col * 32 + ((ks ^ ((col >> 1) & 3)) << 3);
    }
  }

  f32x4 accg[4][2], accv[4][2];
  const f32x4 zero = {0.f, 0.f, 0.f, 0.f};
#pragma unroll
  for (int mi = 0; mi < 4; ++mi)
#pragma unroll
    for (int ni = 0; ni < 2; ++ni) { accg[mi][ni] = zero; accv[mi][ni] = zero; }

#define S1_ISSUE(Q, KO)                                                        \
  do {                                                                         \
    GLOAD16(aga + (KO), (Q) + adb);                                            \
    GLOAD16(bg1 + (KO), (Q) + 4096 + bdb);                                     \
    GLOAD16(bg2 + (KO), (Q) + 8192 + bdb);                                     \
  } while (0)

  S1_ISSUE(lds, 0);
  S1_ISSUE(lds + S1_BUF, 32);
  asm volatile("s_waitcnt vmcnt(3)" ::: "memory");
  __builtin_amdgcn_s_barrier();
  __builtin_amdgcn_sched_barrier(0);

#define S1_STEP(P, KC, ISSUE)                                                  \
  {                                                                            \
    const u16* Ab  = lds + (P) * S1_BUF;                                       \
    const u16* B1b = Ab + 4096;                                                \
    const u16* B2b = Ab + 8192;                                                \
    short8 af[4], b1f[2], b2f[2];                                              \
    _Pragma("unroll") for (int mi = 0; mi < 4; ++mi)                           \
      af[mi] = *(const short8*)(Ab + aoff[mi]);                                \
    _Pragma("unroll") for (int ni = 0; ni < 2; ++ni) {                         \
      b1f[ni] = *(const short8*)(B1b + boff[ni]);                              \
      b2f[ni] = *(const short8*)(B2b + boff[ni]);                              \
    }                                                                          \
    if (ISSUE) S1_ISSUE(lds + (((P) + 2) % 3) * S1_BUF, ((KC) + 2) * 32);      \
    __builtin_amdgcn_s_setprio(1);                                             \
    _Pragma("unroll") for (int mi = 0; mi < 4; ++mi)                           \
      _Pragma("unroll") for (int ni = 0; ni < 2; ++ni) {                       \
        accg[mi][ni] = __builtin_amdgcn_mfma_f32_16x16x32_bf16(                \
            af[mi], b1f[ni], accg[mi][ni], 0, 0, 0);                           \
        accv[mi][ni] = __builtin_amdgcn_mfma_f32_16x16x32_bf16(                \
            af[mi], b2f[ni], accv[mi][ni], 0, 0, 0);                           \
      }                                                                        \
    __builtin_amdgcn_s_setprio(0);                                             \
    if (ISSUE) asm volatile("s_waitcnt vmcnt(3)" ::: "memory");                \
    else       asm volatile("s_waitcnt vmcnt(0)" ::: "memory");                \
    __builtin_amdgcn_s_barrier();                                              \
    __builtin_amdgcn_sched_barrier(0);                                         \
  }

  for (int kc = 0; kc < S1_NK - 2; kc += 3) {
    S1_STEP(0, kc, 1)
    S1_STEP(1, kc + 1, 1)
    S1_STEP(2, kc + 2, 1)
  }
  S1_STEP(0, S1_NK - 2, 0)
  S1_STEP(1, S1_NK - 1, 0)
#undef S1_STEP
#undef S1_ISSUE

  const int prow = r0 + wm * 64 + ((lane >> 4) << 2);
  const int pcol = n0 + wn * 32 + (lane & 15);
#pragma unroll
  for (int mi = 0; mi < 4; ++mi)
#pragma unroll
    for (int ni = 0; ni < 2; ++ni)
#pragma unroll
      for (int j = 0; j < 4; ++j) {
        float g = accg[mi][ni][j];
        float v = accv[mi][ni][j];
        float s = g / (1.f + __expf(-g));
        h[(size_t)(prow + mi * 16 + j) * DFF + (pcol + ni * 16)] = f2bu(s * v);
      }
}

// ---------------- stage 2: out += p * (h @ W3), grouped ----------------
// r16 best-known-good: tile 128x256, BK=32, 3-buffer counted vmcnt(3),
// 2 blocks/CU, bijective XCD-chunked swizzle (nwg = 4*136 = 544 = 8*68),
// atomicAdd epilogue (r17 showed the atomic-free ph+reduce path costs +88us
// in extra HBM traffic: out is L2-resident, atomics are nearly free).

#define S2_BUF 12288   // u16 per buffer: A 4096 (128x32) | B 8192 (256x32)
#define S2_NK  128     // 4096 / 32

__global__ __launch_bounds__(512, 4) void stage2_k(const u16* __restrict__ h,
                                                   const u16* __restrict__ w3t,
                                                   float* __restrict__ out,
                                                   const int* __restrict__ tok,
                                                   const float* __restrict__ wg,
                                                   const int* __restrict__ offp) {
  extern __shared__ __align__(16) u16 lds[];   // 3 * 24576 B = 73728 B
  const int orig = blockIdx.y * 4 + blockIdx.x;     // gridDim = (4, 136)
  const int wgid = (orig & 7) * 68 + (orig >> 3);
  const int bx = wgid & 3, by = wgid >> 2;
  const int r0 = by * 128;
  if (r0 >= offp[NEXP]) return;
  int e = 0;
#pragma unroll
  for (int q = 0; q < 7; ++q) e += (offp[e + 1] <= r0) ? 1 : 0;
  const int n0 = bx * 256;
  const int tid = threadIdx.x;
  const int lane = tid & 63, w = tid >> 6;
  const int wm = w >> 2, wn = w & 3;

  const int sl = lane & 3, rl = lane >> 2;
  const u16* aga;
  int adb;
  {
    int row = w * 16 + rl;
    aga = h + (size_t)(r0 + row) * DFF + ((sl ^ ((row >> 1) & 3)) << 3);
    adb = (w * 16) * 32;
  }
  const u16* w3e = w3t + (size_t)e * DMODEL * DFF;
  const u16* bga[2];
  int bdb[2];
#pragma unroll
  for (int j = 0; j < 2; ++j) {
    int row = w * 32 + j * 16 + rl;
    bga[j] = w3e + (size_t)(n0 + row) * DFF + ((sl ^ ((row >> 1) & 3)) << 3);
    bdb[j] = 4096 + (w * 32 + j * 16) * 32;
  }

  int aoff[4], boff[4];
  {
    int ks = lane >> 4;
#pragma unroll
    for (int mi = 0; mi < 4; ++mi) {
      int row = wm * 64 + mi * 16 + (lane & 15);
      aoff[mi] = row * 32 + ((ks ^ ((row >> 1) & 3)) << 3);
    }
#pragma unroll
    for (int ni = 0; ni < 4; ++ni) {
      int col = wn * 64 + ni * 16 + (lane & 15);
      boff[ni] = 4096 + col * 32 + ((ks ^ ((col >> 1) & 3)) << 3);
    }
  }

  f32x4 acc[4][4];
  const f32x4 zero = {0.f, 0.f, 0.f, 0.f};
#pragma unroll
  for (int mi = 0; mi < 4; ++mi)
#pragma unroll
    for (int ni = 0; ni < 4; ++ni) acc[mi][ni] = zero;

#define S2_ISSUE(Q, KO)                                                        \
  do {                                                                         \
    GLOAD16(aga + (KO), (Q) + adb);                                            \
    GLOAD16(bga[0] + (KO), (Q) + bdb[0]);                                      \
    GLOAD16(bga[1] + (KO), (Q) + bdb[1]);                                      \
  } while (0)

  S2_ISSUE(lds, 0);
  S2_ISSUE(lds + S2_BUF, 32);
  asm volatile("s_waitcnt vmcnt(3)" ::: "memory");
  __builtin_amdgcn_s_barrier();
  __builtin_amdgcn_sched_barrier(0);

#define S2_STEP(P, KC, ISSUE)                                                  \
  {                                                                            \
    const u16* Qb = lds + (P) * S2_BUF;                                        \
    short8 af[4], bf[4];                                                       \
    _Pragma("unroll") for (int mi = 0; mi < 4; ++mi)                           \
      af[mi] = *(const short8*)(Qb + aoff[mi]);                                \
    _Pragma("unroll") for (int ni = 0; ni < 4; ++ni)                           \
      bf[ni] = *(const short8*)(Qb + boff[ni]);                                \
    if (ISSUE) S2_ISSUE(lds + (((P) + 2) % 3) * S2_BUF, ((KC) + 2) * 32);      \
    __builtin_amdgcn_s_setprio(1);                                             \
    _Pragma("unroll") for (int mi = 0; mi < 4; ++mi)                           \
      _Pragma("unroll") for (int ni = 0; ni < 4; ++ni)                         \
        acc[mi][ni] = __builtin_amdgcn_mfma_f32_16x16x32_bf16(                 \
            af[mi], bf[ni], acc[mi][ni], 0, 0, 0);                             \
    __builtin_amdgcn_s_setprio(0);                                             \
    if (ISSUE) asm volatile("s_waitcnt vmcnt(3)" ::: "memory");                \
    else       asm volatile("s_waitcnt vmcnt(0)" ::: "memory");                \
    __builtin_amdgcn_s_barrier();                                              \
    __builtin_amdgcn_sched_barrier(0);                                         \
  }

  for (int kc = 0; kc < S2_NK - 2; kc += 3) {
    S2_STEP(0, kc, 1)
    S2_STEP(1, kc + 1, 1)
    S2_STEP(2, kc + 2, 1)
  }
  S2_STEP(0, S2_NK - 2, 0)
  S2_STEP(1, S2_NK - 1, 0)
#undef S2_STEP
#undef S2_ISSUE

  const int prow = r0 + wm * 64 + ((lane >> 4) << 2);
  const int pcolb = n0 + wn * 64 + (lane & 15);
#pragma unroll
  for (int mi = 0; mi < 4; ++mi)
#pragma unroll
    for (int j = 0; j < 4; ++j) {
      int pos = prow + mi * 16 + j;
      float p = wg[pos];
      if (p != 0.f) {
        int t = tok[pos];
#pragma unroll
        for (int ni = 0; ni < 4; ++ni)
          atomicAdd(&out[(size_t)t * DMODEL + pcolb + ni * 16], p * acc[mi][ni][j]);
      }
    }
}

// ---------------- launch ----------------

extern "C" void kernel_launch(void* const* d_in, const int* in_sizes, int n_in,
                              void* d_out, int out_size, void* d_ws, size_t ws_size,
                              hipStream_t stream) {
  (void)in_sizes; (void)n_in;
  const float* x  = (const float*)d_in[0];
  const int*   ei = (const int*)d_in[1];
  const float* ew = (const float*)d_in[2];
  const float* w1 = (const float*)d_in[3];
  const float* w2 = (const float*)d_in[4];
  const float* w3 = (const float*)d_in[5];
  float* out = (float*)d_out;
  char* ws = (char*)d_ws;

  hipMemsetAsync(out, 0, (size_t)out_size * sizeof(float), stream);
  if (ws_size < WS_END) return;   // ws too small: leave zeros (diagnosable absmax)

  u16* xb   = (u16*)(ws + OFF_XB);
  u16* w1t  = (u16*)(ws + OFF_W1T);
  u16* w2t  = (u16*)(ws + OFF_W2T);
  u16* w3t  = (u16*)(ws + OFF_W3T);
  u16* hb   = (u16*)(ws + OFF_H);
  int* tok  = (int*)(ws + OFF_TOK);
  float* wg = (float*)(ws + OFF_WGT);
  int* offp = (int*)(ws + OFF_OFFP);

  hipFuncSetAttribute(reinterpret_cast<const void*>(stage1_k),
                      hipFuncAttributeMaxDynamicSharedMemorySize, 73728);
  hipFuncSetAttribute(reinterpret_cast<const void*>(stage2_k),
                      hipFuncAttributeMaxDynamicSharedMemorySize, 73728);

  cvt_x_k<<<dim3(NTOK * DMODEL / 4 / 256), 256, 0, stream>>>(x, xb);
  wcvt_k<<<dim3(256, 24), 256, 0, stream>>>(w1, w2, w3, w1t, w2t, w3t);
  route_k<<<dim3(1), 1024, 0, stream>>>(ei, ew, tok, wg, offp);
  stage1_k<<<dim3(DFF / 128, PPAD / 128), 512, 73728, stream>>>(xb, w1t, w2t, hb, tok, offp);
  stage2_k<<<dim3(DMODEL / 256, PPAD / 128), 512, 73728, stream>>>(hb, w3t, out, tok, wg, offp);
}